// Round 5
// baseline (2314.047 us; speedup 1.0000x reference)
//
#include <hip/hip_runtime.h>
#include <cmath>

#define T_STEPS 4096
#define BATCH   128
#define NIN     96
#define NH      64

// f64 decay constants, matching np.exp(-DT/TAU) f64 scalars (NEP-50 promotion)
__device__ __forceinline__ double d_alpha() { return exp(-0.004 / (log1p(exp(1.0)) * 0.01)); }
__device__ __forceinline__ double d_beta()  { return exp(-0.004 / (log1p(exp(1.0)) * 0.02)); }

// ---------------- Phase 1: cur[(t*B+b), h] = seq-fma dot(x[(t-1)*B+b,:], Wh[h,:]) in f32.
// Single accumulator, k ascending, FMA — bit-matches BLAS sgemm microkernel rounding.
// One wave = 16 rows; lane = output neuron h. Wh row in registers, x via broadcast float4.
__global__ __launch_bounds__(256) void k_cur(const float* __restrict__ x,
                                             const float* __restrict__ Wh,
                                             float* __restrict__ cur) {
    const int NBLK = ((T_STEPS - 1) * BATCH) / 64;  // 8190 compute blocks
    if (blockIdx.x == NBLK) {  // rows [0, BATCH): t=0 has prev_inp = 0
        for (int i = threadIdx.x; i < BATCH * NH; i += 256) cur[i] = 0.0f;
        return;
    }
    const int h = threadIdx.x & 63;
    const int wq = threadIdx.x >> 6;
    const size_t row0 = (size_t)blockIdx.x * 64 + (size_t)wq * 16;  // 16 rows per wave
    const float* wp = Wh + h * NIN;
    const float* xp = x + row0 * NIN;

    float c[16];
#pragma unroll
    for (int j = 0; j < 16; ++j) c[j] = 0.0f;

#pragma unroll
    for (int i = 0; i < NIN; i += 4) {
        const float4 w4 = *(const float4*)(wp + i);  // per-lane Wh row chunk (L1-hot)
#pragma unroll
        for (int j = 0; j < 16; ++j) {
            const float4 x4 = *(const float4*)(xp + j * NIN + i);  // wave-broadcast
            c[j] = fmaf(x4.x, w4.x, c[j]);
            c[j] = fmaf(x4.y, w4.y, c[j]);
            c[j] = fmaf(x4.z, w4.z, c[j]);
            c[j] = fmaf(x4.w, w4.w, c[j]);
        }
    }
    float* cp = cur + (row0 + BATCH) * NH + h;  // shift by one timestep
#pragma unroll
    for (int j = 0; j < 16; ++j) cp[(size_t)j * NH] = c[j];
}

// ---------------- Phase 2: sequential scan, f64 hidden states, exact-f64 recurrent sum
// via dense bit-pair lookup tables in LDS (spike-rate independent, no serial load chain).
// 1 block = 1 batch element, 1 wave, lane = hidden neuron.
__global__ __launch_bounds__(64, 1) void k_scan(const float* __restrict__ cur,
                                                const float* __restrict__ V,
                                                _Float16* __restrict__ ftr) {
    const int b = blockIdx.x, h = threadIdx.x;
    const double alpha = d_alpha(), beta = d_beta(), ombeta = 1.0 - beta;
    const float alphaf = (float)alpha, betaf = (float)beta, ombetaf = (float)(1.0 - beta);

    // T2[g][cc][h] = sum of V[h][2g+j] for j set in cc (exact in f64). 31 groups = 63.5 KB.
    __shared__ double T2[31 * 4 * 64];
    const float* vp = V + h * 64;
#pragma unroll
    for (int g = 0; g < 31; ++g) {
        const double v0 = (double)vp[2 * g], v1 = (double)vp[2 * g + 1];
        T2[(g * 4 + 0) * 64 + h] = 0.0;
        T2[(g * 4 + 1) * 64 + h] = v0;
        T2[(g * 4 + 2) * 64 + h] = v1;
        T2[(g * 4 + 3) * 64 + h] = v0 + v1;
    }
    const double v62 = (double)vp[62];
    const double v63 = (double)vp[63];
    __syncthreads();

    double syn = 0.0, mem = 0.0;
    float e = 0.f, f = 0.f, spkf = 0.f;
    unsigned long long mask = 0ull;

    const size_t STEP = (size_t)BATCH * NH;
    const float* cp = cur + (size_t)b * NH + h;
    _Float16* fp = ftr + (size_t)b * NH + h;

    float cbuf[8];  // 8-deep prefetch hides HBM latency on cur reads
#pragma unroll
    for (int j = 0; j < 8; ++j) cbuf[j] = cp[(size_t)j * STEP];

    for (int tt = 0; tt < T_STEPS; tt += 8) {
#pragma unroll
        for (int j = 0; j < 8; ++j) {
            const float c = cbuf[j];
            int tn = tt + j + 8;
            if (tn > T_STEPS - 1) tn = T_STEPS - 1;  // clamped tail loads, unused
            cbuf[j] = cp[(size_t)tn * STEP];

            // rec = sum_{k in prev mask} V[h,k]: 31 independent LDS b64 reads + f64 tree
            const unsigned mlo = (unsigned)mask;
            const unsigned mhi = (unsigned)(mask >> 32);
            double r0 = 0.0, r1 = 0.0, r2 = 0.0, r3 = 0.0;
#pragma unroll
            for (int g = 0; g < 16; ++g) {
                const int cc = (mlo >> (2 * g)) & 3;
                const double tv = T2[((g * 4 + cc) << 6) + h];
                if ((g & 3) == 0) r0 += tv;
                else if ((g & 3) == 1) r1 += tv;
                else if ((g & 3) == 2) r2 += tv;
                else r3 += tv;
            }
#pragma unroll
            for (int g = 0; g < 15; ++g) {
                const int cc = (mhi >> (2 * g)) & 3;
                const double tv = T2[(((g + 16) * 4 + cc) << 6) + h];
                if ((g & 3) == 0) r0 += tv;
                else if ((g & 3) == 1) r1 += tv;
                else if ((g & 3) == 2) r2 += tv;
                else r3 += tv;
            }
            double rec = (r0 + r1) + (r2 + r3);
            rec += (mhi & 0x40000000u) ? v62 : 0.0;
            rec += (mhi & 0x80000000u) ? v63 : 0.0;

            syn = alpha * syn + ((double)c + rec);
            mem = beta * mem + ombeta * syn;

            // readout traces driven by PREVIOUS spikes (before this step's mask update)
            e = fmaf(alphaf, e, spkf);
            f = fmaf(betaf, f, ombetaf * e);
            fp[(size_t)(tt + j) * STEP] = (_Float16)f;

            const bool s = mem > 1.0;
            mem = s ? 0.0 : mem;
            spkf = s ? 1.0f : 0.0f;
            mask = __ballot(s);
        }
    }
}

// ---------------- Phase 3: preds[t,b,o] = sum_h Wo[o,h]*f[t,b,h] -> f32 [T,B,2].
__global__ __launch_bounds__(256) void k_out(const _Float16* __restrict__ ftr,
                                             const float* __restrict__ Wo,
                                             float* __restrict__ out) {
    __shared__ float wo[2][64];
    const int tid = threadIdx.x;
    if (tid < 128) wo[tid >> 6][tid & 63] = Wo[tid];
    __syncthreads();

    const size_t idx = (size_t)blockIdx.x * 256 + tid;  // row = t*B + b
    const uint4* up = (const uint4*)(ftr + idx * NH);
    float d0 = 0.f, d1 = 0.f;
#pragma unroll
    for (int j = 0; j < 8; ++j) {
        const uint4 u = up[j];
        const unsigned w[4] = {u.x, u.y, u.z, u.w};
#pragma unroll
        for (int q = 0; q < 4; ++q) {
            const int k = j * 8 + q * 2;
            const float f0 = (float)__builtin_bit_cast(_Float16, (unsigned short)(w[q] & 0xFFFFu));
            const float f1 = (float)__builtin_bit_cast(_Float16, (unsigned short)(w[q] >> 16));
            d0 = fmaf(f0, wo[0][k], d0);
            d1 = fmaf(f0, wo[1][k], d1);
            d0 = fmaf(f1, wo[0][k + 1], d0);
            d1 = fmaf(f1, wo[1][k + 1], d1);
        }
    }
    float2 r; r.x = d0; r.y = d1;
    ((float2*)out)[idx] = r;
}

// ---------------- Fallback: fully fused, zero workspace, f64 states, f32 output.
__global__ __launch_bounds__(64) void k_fused(const float* __restrict__ x,
                                              const float* __restrict__ Wh,
                                              const float* __restrict__ V,
                                              const float* __restrict__ Wo,
                                              float* __restrict__ out) {
    const int b = blockIdx.x, h = threadIdx.x;
    const double alpha = d_alpha(), beta = d_beta(), ombeta = 1.0 - beta;

    __shared__ float vlds[NH * NH];  // vlds[k*64+h] = V[h][k]
    __shared__ float whl[NIN * NH];  // whl[i*64+h] = Wh[h][i]
    for (int s = h; s < NH * NH; s += 64) vlds[((s & 63) << 6) | (s >> 6)] = V[s];
    for (int s = h; s < NH * NIN; s += 64) whl[(s % 96) * 64 + (s / 96)] = Wh[s];
    __syncthreads();

    const double wo0 = (double)Wo[h], wo1 = (double)Wo[64 + h];

    double syn = 0.0, mem = 0.0, syno0 = 0.0, memo0 = 0.0, syno1 = 0.0, memo1 = 0.0;
    double spkd = 0.0;
    unsigned long long mask = 0ull;

    for (int t = 0; t < T_STEPS; ++t) {
        float c = 0.0f;
        if (t > 0) {
            const float* xp = x + ((size_t)(t - 1) * BATCH + b) * NIN;
            for (int i = 0; i < NIN; ++i) c = fmaf(xp[i], whl[i * 64 + h], c);
        }
        double rec = 0.0;
        unsigned long long m = mask;
        while (m) { const int k = __builtin_ctzll(m); m &= m - 1; rec += (double)vlds[(k << 6) | h]; }

        syn = alpha * syn + ((double)c + rec);
        mem = beta * mem + ombeta * syn;

        double p0 = spkd * wo0, p1 = spkd * wo1;
#pragma unroll
        for (int d = 32; d >= 1; d >>= 1) { p0 += __shfl_xor(p0, d, 64); p1 += __shfl_xor(p1, d, 64); }
        syno0 = alpha * syno0 + p0;
        memo0 = beta * memo0 + ombeta * syno0;
        syno1 = alpha * syno1 + p1;
        memo1 = beta * memo1 + ombeta * syno1;
        if (h == 0) {
            const size_t w = ((size_t)t * BATCH + b) * 2;
            out[w] = (float)memo0;
            out[w + 1] = (float)memo1;
        }

        const bool s = mem > 1.0;
        mem = s ? 0.0 : mem;
        spkd = s ? 1.0 : 0.0;
        mask = __ballot(s);
    }
}

extern "C" void kernel_launch(void* const* d_in, const int* in_sizes, int n_in,
                              void* d_out, int out_size, void* d_ws, size_t ws_size,
                              hipStream_t stream) {
    (void)in_sizes; (void)out_size;
    if (n_in < 4) return;
    const float* x  = (const float*)d_in[0];   // [T,B,IN]  f32
    const float* Wh = (const float*)d_in[1];   // [H,IN]    f32
    const float* V  = (const float*)d_in[2];   // [H,H]     f32
    const float* Wo = (const float*)d_in[3];   // [OUT,H]   f32
    float* out = (float*)d_out;                // [T,B,2]   f32

    const size_t NROW = (size_t)T_STEPS * BATCH;       // 524288
    const size_t curB = NROW * NH * sizeof(float);     // 134 MB
    const size_t ftrB = NROW * NH * sizeof(_Float16);  // 67 MB

    if (ws_size >= curB + ftrB) {
        float* cur = (float*)d_ws;
        _Float16* ftr = (_Float16*)((char*)d_ws + curB);
        const int NBLK = ((T_STEPS - 1) * BATCH) / 64 + 1;  // 8191 incl. zero block
        k_cur<<<NBLK, 256, 0, stream>>>(x, Wh, cur);
        k_scan<<<BATCH, 64, 0, stream>>>(cur, V, ftr);
        k_out<<<NROW / 256, 256, 0, stream>>>(ftr, Wo, out);
    } else {
        k_fused<<<BATCH, 64, 0, stream>>>(x, Wh, V, Wo, out);
    }
}